// Round 6
// baseline (163.198 us; speedup 1.0000x reference)
//
#include <hip/hip_runtime.h>
#include <hip/hip_bf16.h>
#include <stdint.h>

#define BM 128
#define BN 128
#define BK 64

typedef __attribute__((ext_vector_type(8))) short bf16x8;
typedef __attribute__((ext_vector_type(4))) float f32x4;
typedef unsigned short ushort_t;

__device__ inline unsigned short f2b(float f) {
  unsigned u = __float_as_uint(f);
  unsigned r = (u + 0x7FFFu + ((u >> 16) & 1u)) >> 16;   // RNE, finite inputs
  return (unsigned short)r;
}

__device__ inline void gload_lds16(const void* g, void* l) {
  __builtin_amdgcn_global_load_lds(
      (const __attribute__((address_space(1))) void*)g,
      (__attribute__((address_space(3))) void*)l, 16, 0, 0);
}

// ---------------- f32 -> bf16 convert, 4 elems/thread ----------------
__global__ __launch_bounds__(256) void cvt_kernel(const float* __restrict__ in,
                                                  ushort_t* __restrict__ out, int n) {
  int i = (blockIdx.x * blockDim.x + threadIdx.x) * 4;
  int stride = gridDim.x * blockDim.x * 4;
  for (; i < n; i += stride) {
    float4 v = *(const float4*)(in + i);
    ushort4 o;
    o.x = f2b(v.x); o.y = f2b(v.y); o.z = f2b(v.z); o.w = f2b(v.w);
    *(ushort4*)(out + i) = o;
  }
}

// convert 3 same-size f32 arrays into one contiguous bf16 buffer
__global__ __launch_bounds__(256) void cvt3_kernel(const float* __restrict__ a,
                                                   const float* __restrict__ b,
                                                   const float* __restrict__ c,
                                                   ushort_t* __restrict__ out, int n_each) {
  const float* src = blockIdx.y == 0 ? a : (blockIdx.y == 1 ? b : c);
  ushort_t* dst = out + (size_t)blockIdx.y * n_each;
  int i = (blockIdx.x * blockDim.x + threadIdx.x) * 4;
  int stride = gridDim.x * blockDim.x * 4;
  for (; i < n_each; i += stride) {
    float4 v = *(const float4*)(src + i);
    ushort4 o;
    o.x = f2b(v.x); o.y = f2b(v.y); o.z = f2b(v.z); o.w = f2b(v.w);
    *(ushort4*)(dst + i) = o;
  }
}

__global__ __launch_bounds__(256) void concat3_f32(const float* __restrict__ a,
                                                   const float* __restrict__ b,
                                                   const float* __restrict__ c,
                                                   float* __restrict__ out, int n) {
  int i = blockIdx.x * blockDim.x + threadIdx.x;
  if (i < n) { out[i] = a[i]; out[n + i] = b[i]; out[2 * n + i] = c[i]; }
}

// stage one [128 rows][64 cols] bf16 half-tile: 512 thr x 2 gload_lds of 16B.
// global source col pre-swizzled so linear LDS dest + swizzled read match.
__device__ inline void stage_half(const ushort_t* __restrict__ G, int ldg,
                                  ushort_t* slot, int w, int lane, int koff) {
  int r = w * 16 + (lane >> 3);
  int scol = ((lane & 7) ^ (lane >> 3)) << 3;  // pre-swizzled source col (elems)
  const ushort_t* src = G + (size_t)r * ldg + koff + scol;
  gload_lds16(src, slot + w * 16 * 64);
  gload_lds16(src + (size_t)8 * ldg, slot + (w * 16 + 8) * 64);
}

#define SBAR0() __builtin_amdgcn_sched_barrier(0)
#define PH_BAR() do { SBAR0(); __builtin_amdgcn_s_barrier(); SBAR0(); } while (0)
#define LGKM0() do { asm volatile("s_waitcnt lgkmcnt(0)" ::: "memory"); SBAR0(); } while (0)

// ============ 256x256 4-phase K-loop machinery (m201 template port) ============
#define LDA_SUB(mh)                                                              \
  _Pragma("unroll") for (int mf = 0; mf < 4; ++mf)                               \
  _Pragma("unroll") for (int ks = 0; ks < 2; ++ks) {                             \
    int r_ = (mh) * 128 + wr * 64 + mf * 16 + fr;                                \
    a[mf][ks] = *(const bf16x8*)(LA + r_ * 128 + ((ks * 64 + g16) ^ ((r_ & 7) << 4))); \
  }

#define LDB_SUB(dst, nh)                                                         \
  _Pragma("unroll") for (int nf = 0; nf < 2; ++nf)                               \
  _Pragma("unroll") for (int ks = 0; ks < 2; ++ks) {                             \
    int r_ = (nh) * 128 + wc * 32 + nf * 16 + fr;                                \
    dst[nf][ks] = *(const bf16x8*)(LB + r_ * 128 + ((ks * 64 + g16) ^ ((r_ & 7) << 4))); \
  }

#define MFMA_Q(mh, nh, bq)                                                       \
  __builtin_amdgcn_s_setprio(1);                                                 \
  _Pragma("unroll") for (int mf = 0; mf < 4; ++mf)                               \
  _Pragma("unroll") for (int nf = 0; nf < 2; ++nf)                               \
  _Pragma("unroll") for (int ks = 0; ks < 2; ++ks)                               \
    acc[(mh) * 4 + mf][(nh) * 2 + nf] = __builtin_amdgcn_mfma_f32_16x16x32_bf16( \
        a[mf][ks], bq[nf][ks], acc[(mh) * 4 + mf][(nh) * 2 + nf], 0, 0, 0);      \
  __builtin_amdgcn_s_setprio(0);

#define KLOOP_256(ldaK, ldbK)                                                    \
  stage_half(A0g, ldaK, &lds[0][0][0], w, lane, 0);                              \
  stage_half(A1g, ldaK, &lds[0][1][0], w, lane, 0);                              \
  stage_half(B0g, ldbK, &lds[0][2][0], w, lane, 0);                              \
  stage_half(B1g, ldbK, &lds[0][3][0], w, lane, 0);                              \
  if (nt > 1) {                                                                  \
    stage_half(A0g, ldaK, &lds[1][0][0], w, lane, 64);                           \
    stage_half(B0g, ldbK, &lds[1][2][0], w, lane, 64);                           \
    stage_half(B1g, ldbK, &lds[1][3][0], w, lane, 64);                           \
    asm volatile("s_waitcnt vmcnt(6)" ::: "memory");                             \
  } else {                                                                       \
    asm volatile("s_waitcnt vmcnt(0)" ::: "memory");                             \
  }                                                                              \
  PH_BAR();                                                                      \
  for (int t = 0; t < nt; ++t) {                                                 \
    const int cur = t & 1, nxt = cur ^ 1;                                        \
    const char* LA = (const char*)&lds[cur][0][0];                               \
    const char* LB = (const char*)&lds[cur][2][0];                               \
    bf16x8 a[4][2], b0[2][2], b1[2][2];                                          \
    LDA_SUB(0);                                                                  \
    LDB_SUB(b0, 0);                                                              \
    if (t + 1 < nt) stage_half(A1g, ldaK, &lds[nxt][1][0], w, lane, (t + 1) * 64); \
    asm volatile("s_waitcnt lgkmcnt(8)" ::: "memory");                           \
    PH_BAR();                                                                    \
    LGKM0();                                                                     \
    MFMA_Q(0, 0, b0);                                                            \
    PH_BAR();                                                                    \
    LDB_SUB(b1, 1);                                                              \
    if (t + 2 < nt) stage_half(A0g, ldaK, &lds[cur][0][0], w, lane, (t + 2) * 64); \
    PH_BAR();                                                                    \
    LGKM0();                                                                     \
    MFMA_Q(0, 1, b1);                                                            \
    PH_BAR();                                                                    \
    LDA_SUB(1);                                                                  \
    if (t + 2 < nt) stage_half(B0g, ldbK, &lds[cur][2][0], w, lane, (t + 2) * 64); \
    PH_BAR();                                                                    \
    LGKM0();                                                                     \
    MFMA_Q(1, 1, b1);                                                            \
    PH_BAR();                                                                    \
    if (t + 2 < nt) {                                                            \
      stage_half(B1g, ldbK, &lds[cur][3][0], w, lane, (t + 2) * 64);             \
      asm volatile("s_waitcnt vmcnt(6)" ::: "memory");                           \
    } else if (t + 1 < nt) {                                                     \
      asm volatile("s_waitcnt vmcnt(0)" ::: "memory");                           \
    }                                                                            \
    PH_BAR();                                                                    \
    MFMA_Q(1, 0, b0);                                                            \
    PH_BAR();                                                                    \
  }

// ---------------- scores: P = exp((Q @ K^T) * scale) causal, + rowsum atomics ----------------
// grid (S/256 cols, S/256 rows, batch); skips bx>by; 1024-deep K (feature dim).
__global__ __launch_bounds__(512, 1) void score256(
    const ushort_t* __restrict__ A, const ushort_t* __restrict__ B,
    ushort_t* __restrict__ P, float* __restrict__ rowsum,
    int M, int K, int lda, int ldb, int ldc,
    long bsA, long bsB, long bsC, float scale) {
  int bx = blockIdx.x, by = blockIdx.y, bz = blockIdx.z;
  if (bx > by) return;  // fully-masked causal block: never touched

  __shared__ __align__(16) ushort_t lds[2][4][128 * 64];  // 128 KiB

  int tid = threadIdx.x, lane = tid & 63, w = tid >> 6;
  int wr = w >> 2, wc = w & 3;
  int fr = lane & 15, g16 = (lane >> 4) * 16;

  const ushort_t* Ab = A + (size_t)bz * bsA + (size_t)by * 256 * lda;
  const ushort_t* Bb = B + (size_t)bz * bsB + (size_t)bx * 256 * ldb;
  const ushort_t* A0g = Ab;
  const ushort_t* A1g = Ab + (size_t)128 * lda;
  const ushort_t* B0g = Bb;
  const ushort_t* B1g = Bb + (size_t)128 * ldb;

  f32x4 acc[8][4];
#pragma unroll
  for (int i = 0; i < 8; i++)
#pragma unroll
    for (int j = 0; j < 4; j++) acc[i][j] = (f32x4)(0.f);

  int nt = K >> 6;
  KLOOP_256(lda, ldb);

  // epilogue: exp + causal mask + per-row sums (atomic)
  ushort_t* Cp = P + (size_t)bz * bsC;
  int c2 = lane & 15;
  int rb = (lane >> 4) * 4;
#pragma unroll
  for (int mi = 0; mi < 8; ++mi) {
    int mh = mi >> 2, mf = mi & 3;
#pragma unroll
    for (int j = 0; j < 4; ++j) {
      int row = by * 256 + mh * 128 + wr * 64 + mf * 16 + rb + j;
      float rsum = 0.f;
#pragma unroll
      for (int ni = 0; ni < 4; ++ni) {
        int nh = ni >> 1, nf = ni & 1;
        int col = bx * 256 + nh * 128 + wc * 32 + nf * 16 + c2;
        float e = 0.f;
        if (bx != by || col <= row) e = __expf(acc[mi][ni][j] * scale);
        rsum += e;
        Cp[(size_t)row * ldc + col] = f2b(e);
      }
#pragma unroll
      for (int o = 1; o < 16; o <<= 1) rsum += __shfl_xor(rsum, o);
      if (c2 == 0) atomicAdd(&rowsum[(size_t)bz * M + row], rsum);
    }
  }
}

#undef LDA_SUB
#undef LDB_SUB
#undef MFMA_Q
#undef PH_BAR
#undef LGKM0
#undef SBAR0
#undef KLOOP_256

// ---------------- 128x128 GEMM  C = A @ B^T  (A:[M][K], B:[N][K], bf16) ----------------
// BK=64, XOR-swizzled LDS; 32 MFMA per barrier; ~3 blocks/CU (cross-block
// overlap hides stage/drain stalls -- the multi-block occupancy structure).
// MODE 0: C bf16 = acc + bias[col]  (projection; 'rowsum' arg = bias, bz=0)
// MODE 2: C f32  = acc / rowsum[row], K capped at (by+1)*BM (PV, causal-zero P tail)
template <int MODE>
__global__ __launch_bounds__(256, 3) void gemm_bt(
    const ushort_t* __restrict__ A, const ushort_t* __restrict__ B,
    void* __restrict__ Cv, float* __restrict__ rowsum,
    int M, int N, int K, int lda, int ldb, int ldc,
    long bsA, long bsB, long bsC, float scale) {
  int bx = blockIdx.x, by = blockIdx.y, bz = blockIdx.z;

  const ushort_t* Ab = A + (size_t)bz * bsA + (size_t)by * BM * lda;
  const ushort_t* Bb = B + (size_t)bz * bsB + (size_t)bx * BN * ldb;

  int Keff = K;
  if (MODE == 2) { int cap = (by + 1) * BM; Keff = cap < K ? cap : K; }

  __shared__ __align__(16) ushort_t As[BM * BK];  // 16 KiB
  __shared__ __align__(16) ushort_t Bs[BN * BK];  // 16 KiB

  int tid = threadIdx.x;
  int lane = tid & 63;
  int w = tid >> 6;                 // 4 waves
  int wm = w >> 1, wn = w & 1;

  f32x4 acc[4][4];
#pragma unroll
  for (int i = 0; i < 4; i++)
#pragma unroll
    for (int j = 0; j < 4; j++) acc[i][j] = (f32x4)(0.f);

  // staging: wave w covers rows w*32 .. w*32+31 (4 gload_lds of 8 rows each)
  int srow = lane >> 3;                      // 0..7 within 8-row group
  int scol = ((lane & 7) ^ srow) << 3;       // pre-swizzled source col (elems)
  int fr = lane & 15, g16 = (lane >> 4) * 16;

  int nk = Keff / BK;
  for (int kt = 0; kt < nk; ++kt) {
    const ushort_t* Abase = Ab + (size_t)(w * 32 + srow) * lda + kt * BK + scol;
    const ushort_t* Bbase = Bb + (size_t)(w * 32 + srow) * ldb + kt * BK + scol;
#pragma unroll
    for (int j = 0; j < 4; ++j) {
      gload_lds16(Abase + (size_t)(j * 8) * lda, &As[(w * 32 + j * 8) * BK]);
      gload_lds16(Bbase + (size_t)(j * 8) * ldb, &Bs[(w * 32 + j * 8) * BK]);
    }
    __syncthreads();

    bf16x8 af[4][2], bf[4][2];
#pragma unroll
    for (int i = 0; i < 4; i++)
#pragma unroll
      for (int ks = 0; ks < 2; ++ks) {
        int ra = wm * 64 + i * 16 + fr;
        af[i][ks] = *(const bf16x8*)((const char*)As + ra * 128 +
                                     ((ks * 64 + g16) ^ ((ra & 7) << 4)));
        int rb2 = wn * 64 + i * 16 + fr;
        bf[i][ks] = *(const bf16x8*)((const char*)Bs + rb2 * 128 +
                                     ((ks * 64 + g16) ^ ((rb2 & 7) << 4)));
      }
#pragma unroll
    for (int mi = 0; mi < 4; mi++)
#pragma unroll
      for (int ni = 0; ni < 4; ni++)
#pragma unroll
        for (int ks = 0; ks < 2; ++ks)
          acc[mi][ni] = __builtin_amdgcn_mfma_f32_16x16x32_bf16(
              af[mi][ks], bf[ni][ks], acc[mi][ni], 0, 0, 0);
    __syncthreads();
  }

  int c = lane & 15;
  int rb = (lane >> 4) * 4;
  if (MODE == 0) {
    ushort_t* Cp = (ushort_t*)Cv;
    float bv4[4];
#pragma unroll
    for (int ni = 0; ni < 4; ni++) bv4[ni] = rowsum[bx * BN + wn * 64 + ni * 16 + c];
#pragma unroll
    for (int mi = 0; mi < 4; mi++)
#pragma unroll
      for (int j = 0; j < 4; j++) {
        int row = by * BM + wm * 64 + mi * 16 + rb + j;
#pragma unroll
        for (int ni = 0; ni < 4; ni++) {
          int col = bx * BN + wn * 64 + ni * 16 + c;
          Cp[(size_t)row * ldc + col] = f2b(acc[mi][ni][j] + bv4[ni]);
        }
      }
  } else {
    float* C = (float*)Cv + (size_t)bz * bsC;
#pragma unroll
    for (int mi = 0; mi < 4; mi++)
#pragma unroll
      for (int j = 0; j < 4; j++) {
        int row = by * BM + wm * 64 + mi * 16 + rb + j;
        float inv = 1.0f / rowsum[(size_t)bz * M + row];
#pragma unroll
        for (int ni = 0; ni < 4; ni++) {
          int col = bx * BN + wn * 64 + ni * 16 + c;
          C[(size_t)row * ldc + col] = acc[mi][ni][j] * inv;
        }
      }
  }
}

// ---------------- bf16 transpose, 64x64 tiles (128B coalesced both sides) ----------------
__global__ __launch_bounds__(256) void transpose2d(const ushort_t* __restrict__ in,
                                                   ushort_t* __restrict__ out,
                                                   int rows, int cols, int ld_in,
                                                   long bs_in, long bs_out) {
  __shared__ ushort_t tile[64][66];
  int b = blockIdx.z;
  in += (size_t)b * bs_in;
  out += (size_t)b * bs_out;
  int c0 = blockIdx.x * 64, r0 = blockIdx.y * 64;
  int tx = threadIdx.x & 31, ty = threadIdx.x >> 5;
#pragma unroll
  for (int i = ty; i < 64; i += 8) {
    ushort2 v = *(const ushort2*)&in[(size_t)(r0 + i) * ld_in + c0 + 2 * tx];
    tile[i][2 * tx] = v.x;
    tile[i][2 * tx + 1] = v.y;
  }
  __syncthreads();
#pragma unroll
  for (int i = ty; i < 64; i += 8) {
    ushort2 o;
    o.x = tile[2 * tx][i];
    o.y = tile[2 * tx + 1][i];
    *(ushort2*)&out[(size_t)(c0 + i) * rows + r0 + 2 * tx] = o;
  }
}

extern "C" void kernel_launch(void* const* d_in, const int* in_sizes, int n_in,
                              void* d_out, int out_size, void* d_ws, size_t ws_size,
                              hipStream_t stream) {
  const int Bb = 4, S = 2048, E = 1024, A = 1024;
  const int N3 = 3 * A;             // fused projection width 3072
  const size_t M = (size_t)Bb * S;  // 8192
  const float* emb = (const float*)d_in[0];
  const float* Wq = (const float*)d_in[1];
  const float* bq = (const float*)d_in[2];
  const float* Wk = (const float*)d_in[3];
  const float* bk = (const float*)d_in[4];
  const float* Wv = (const float*)d_in[5];
  const float* bv = (const float*)d_in[6];
  float* out = (float*)d_out;

  char* ws = (char*)d_ws;
  // layout (byte offsets):
  ushort_t* QKV  = (ushort_t*)(ws + 0);           // 48 MiB [8192][3072]: Q|K|V
  ushort_t* Vt   = (ushort_t*)(ws + 50331648);    // 16 MiB [b][A][S]
  ushort_t* P    = (ushort_t*)(ws + 67108864);    // 32 MiB [b][S][S] bf16 (unnormalized exp)
  float* rowsum  = (float*)(ws + 100663296);      // 32 KiB [b*S]
  ushort_t* embB = (ushort_t*)(ws + 100696064);   // 16 MiB
  ushort_t* WB   = (ushort_t*)(ws + 117473280);   // 6 MiB = Wq|Wk|Wv bf16 [3072][1024]
  float*    bqkv = (float*)(ws + 123764736);      // 12 KiB
  if (ws_size < 157286400ull) return;             // refuse to corrupt

  cvt_kernel<<<2048, 256, 0, stream>>>(emb, embB, (int)(M * E));
  cvt3_kernel<<<dim3(256, 3), 256, 0, stream>>>(Wq, Wk, Wv, WB, A * E);
  concat3_f32<<<4, 256, 0, stream>>>(bq, bk, bv, bqkv, A);
  hipMemsetAsync(rowsum, 0, (size_t)M * sizeof(float), stream);

  // fused QKV projection: M=8192, N=3072, K=1024 -> 24x64 = 1536 blocks, ~3/CU
  gemm_bt<0><<<dim3(N3 / BN, M / BM, 1), dim3(256), 0, stream>>>(
      embB, WB, QKV, bqkv, (int)M, N3, E, E, E, N3, 0, 0, 0, 1.f);

  // V (cols 2048..3071 of QKV, ld 3072) -> Vt [A][S] per batch
  transpose2d<<<dim3(A / 64, S / 64, Bb), dim3(256), 0, stream>>>(
      QKV + 2 * A, Vt, S, A, N3, (long)S * N3, (long)A * S);

  // scores -> P = exp(QK^T/sqrt(dk)) bf16 + rowsum atomics (256^2 4-phase)
  score256<<<dim3(S / 256, S / 256, Bb), dim3(512), 0, stream>>>(
      QKV /*Q*/, QKV + A /*K*/, P, rowsum, S, E, N3, N3, S,
      (long)S * N3, (long)S * N3, (long)S * S, 0.03125f);

  // PV: per batch M=2048, N=1024, K=2048 (capped per block-row), divide by rowsum
  gemm_bt<2><<<dim3(A / BN, S / BM, Bb), dim3(256), 0, stream>>>(
      P, Vt, out, rowsum, S, A, S, S, S, A,
      (long)S * S, (long)A * S, (long)S * A, 1.f);
}

// Round 7
// 153.120 us; speedup vs baseline: 1.0658x; 1.0658x over previous
//
#include <hip/hip_runtime.h>
#include <hip/hip_bf16.h>
#include <stdint.h>
#include <math.h>

#define BM 128
#define BN 128
#define BK 64

typedef __attribute__((ext_vector_type(8))) short bf16x8;
typedef __attribute__((ext_vector_type(4))) float f32x4;
typedef unsigned short ushort_t;

__device__ inline unsigned short f2b(float f) {
  unsigned u = __float_as_uint(f);
  unsigned r = (u + 0x7FFFu + ((u >> 16) & 1u)) >> 16;   // RNE, finite inputs
  return (unsigned short)r;
}

__device__ inline void gload_lds16(const void* g, void* l) {
  __builtin_amdgcn_global_load_lds(
      (const __attribute__((address_space(1))) void*)g,
      (__attribute__((address_space(3))) void*)l, 16, 0, 0);
}

// ---------------- f32 -> bf16 convert, 4 elems/thread ----------------
__global__ __launch_bounds__(256) void cvt_kernel(const float* __restrict__ in,
                                                  ushort_t* __restrict__ out, int n) {
  int i = (blockIdx.x * blockDim.x + threadIdx.x) * 4;
  int stride = gridDim.x * blockDim.x * 4;
  for (; i < n; i += stride) {
    float4 v = *(const float4*)(in + i);
    ushort4 o;
    o.x = f2b(v.x); o.y = f2b(v.y); o.z = f2b(v.z); o.w = f2b(v.w);
    *(ushort4*)(out + i) = o;
  }
}

// convert 3 same-size f32 arrays into one contiguous bf16 buffer
__global__ __launch_bounds__(256) void cvt3_kernel(const float* __restrict__ a,
                                                   const float* __restrict__ b,
                                                   const float* __restrict__ c,
                                                   ushort_t* __restrict__ out, int n_each) {
  const float* src = blockIdx.y == 0 ? a : (blockIdx.y == 1 ? b : c);
  ushort_t* dst = out + (size_t)blockIdx.y * n_each;
  int i = (blockIdx.x * blockDim.x + threadIdx.x) * 4;
  int stride = gridDim.x * blockDim.x * 4;
  for (; i < n_each; i += stride) {
    float4 v = *(const float4*)(src + i);
    ushort4 o;
    o.x = f2b(v.x); o.y = f2b(v.y); o.z = f2b(v.z); o.w = f2b(v.w);
    *(ushort4*)(dst + i) = o;
  }
}

__global__ __launch_bounds__(256) void concat3_f32(const float* __restrict__ a,
                                                   const float* __restrict__ b,
                                                   const float* __restrict__ c,
                                                   float* __restrict__ out, int n) {
  int i = blockIdx.x * blockDim.x + threadIdx.x;
  if (i < n) { out[i] = a[i]; out[n + i] = b[i]; out[2 * n + i] = c[i]; }
}

// ---------------- 128x128 GEMM  C = A @ B^T  (A:[M][K], B:[N][K], bf16) ----------------
// BK=64, XOR-swizzled LDS (pre-swizzled global source + swizzled frag read);
// 32 MFMA per barrier; ~3 blocks/CU (cross-block overlap hides stage/drain).
// MODE 0: C bf16 = acc + bias[col]   (projection; 'rowsum' arg = bias, bz=0)
// MODE 1: P bf16 = exp(acc*scale) causal; rowsum atomics.  Grid x = 136 =
//         packed lower-triangle index per batch (8x17 -> bijective XCD-chunk
//         swizzle: each XCD gets 17 consecutive triangle indices -> shared
//         Q-panels stay in its private L2, cutting panel refetch).
// MODE 2: C f32  = acc / rowsum[row], K capped at (by+1)*BM (PV)
template <int MODE>
__global__ __launch_bounds__(256, 3) void gemm_bt(
    const ushort_t* __restrict__ A, const ushort_t* __restrict__ B,
    void* __restrict__ Cv, float* __restrict__ rowsum,
    int M, int N, int K, int lda, int ldb, int ldc,
    long bsA, long bsB, long bsC, float scale) {
  int bx, by, bz = blockIdx.z;
  if (MODE == 1) {
    // bijective XCD chunk swizzle over 136 blocks, then triangle index -> (by,bx)
    int sw = (blockIdx.x & 7) * 17 + (blockIdx.x >> 3);
    int r = (int)floorf((sqrtf(8.0f * sw + 1.0f) - 1.0f) * 0.5f);
    while ((r + 1) * (r + 2) / 2 <= sw) ++r;
    while (r * (r + 1) / 2 > sw) --r;
    by = r;
    bx = sw - r * (r + 1) / 2;     // bx <= by guaranteed
  } else {
    bx = blockIdx.x;
    by = blockIdx.y;
  }

  const ushort_t* Ab = A + (size_t)bz * bsA + (size_t)by * BM * lda;
  const ushort_t* Bb = B + (size_t)bz * bsB + (size_t)bx * BN * ldb;

  int Keff = K;
  if (MODE == 2) { int cap = (by + 1) * BM; Keff = cap < K ? cap : K; }

  __shared__ __align__(16) ushort_t As[BM * BK];  // 16 KiB
  __shared__ __align__(16) ushort_t Bs[BN * BK];  // 16 KiB

  int tid = threadIdx.x;
  int lane = tid & 63;
  int w = tid >> 6;                 // 4 waves
  int wm = w >> 1, wn = w & 1;

  f32x4 acc[4][4];
#pragma unroll
  for (int i = 0; i < 4; i++)
#pragma unroll
    for (int j = 0; j < 4; j++) acc[i][j] = (f32x4)(0.f);

  // staging: wave w covers rows w*32 .. w*32+31 (4 gload_lds of 8 rows each)
  int srow = lane >> 3;                      // 0..7 within 8-row group
  int scol = ((lane & 7) ^ srow) << 3;       // pre-swizzled source col (elems)
  int fr = lane & 15, g16 = (lane >> 4) * 16;

  int nk = Keff / BK;
  for (int kt = 0; kt < nk; ++kt) {
    const ushort_t* Abase = Ab + (size_t)(w * 32 + srow) * lda + kt * BK + scol;
    const ushort_t* Bbase = Bb + (size_t)(w * 32 + srow) * ldb + kt * BK + scol;
#pragma unroll
    for (int j = 0; j < 4; ++j) {
      gload_lds16(Abase + (size_t)(j * 8) * lda, &As[(w * 32 + j * 8) * BK]);
      gload_lds16(Bbase + (size_t)(j * 8) * ldb, &Bs[(w * 32 + j * 8) * BK]);
    }
    __syncthreads();

    bf16x8 af[4][2], bf[4][2];
#pragma unroll
    for (int i = 0; i < 4; i++)
#pragma unroll
      for (int ks = 0; ks < 2; ++ks) {
        int ra = wm * 64 + i * 16 + fr;
        af[i][ks] = *(const bf16x8*)((const char*)As + ra * 128 +
                                     ((ks * 64 + g16) ^ ((ra & 7) << 4)));
        int rb2 = wn * 64 + i * 16 + fr;
        bf[i][ks] = *(const bf16x8*)((const char*)Bs + rb2 * 128 +
                                     ((ks * 64 + g16) ^ ((rb2 & 7) << 4)));
      }
#pragma unroll
    for (int mi = 0; mi < 4; mi++)
#pragma unroll
      for (int ni = 0; ni < 4; ni++)
#pragma unroll
        for (int ks = 0; ks < 2; ++ks)
          acc[mi][ni] = __builtin_amdgcn_mfma_f32_16x16x32_bf16(
              af[mi][ks], bf[ni][ks], acc[mi][ni], 0, 0, 0);
    __syncthreads();
  }

  int c = lane & 15;
  int rb = (lane >> 4) * 4;
  if (MODE == 0) {
    ushort_t* Cp = (ushort_t*)Cv;
    float bv4[4];
#pragma unroll
    for (int ni = 0; ni < 4; ni++) bv4[ni] = rowsum[bx * BN + wn * 64 + ni * 16 + c];
#pragma unroll
    for (int mi = 0; mi < 4; mi++)
#pragma unroll
      for (int j = 0; j < 4; j++) {
        int row = by * BM + wm * 64 + mi * 16 + rb + j;
#pragma unroll
        for (int ni = 0; ni < 4; ni++) {
          int col = bx * BN + wn * 64 + ni * 16 + c;
          Cp[(size_t)row * ldc + col] = f2b(acc[mi][ni][j] + bv4[ni]);
        }
      }
  } else if (MODE == 1) {
    ushort_t* Cp = (ushort_t*)Cv + (size_t)bz * bsC;
#pragma unroll
    for (int mi = 0; mi < 4; mi++)
#pragma unroll
      for (int j = 0; j < 4; j++) {
        int row = by * BM + wm * 64 + mi * 16 + rb + j;
        float rsum = 0.f;
#pragma unroll
        for (int ni = 0; ni < 4; ni++) {
          int col = bx * BN + wn * 64 + ni * 16 + c;
          float e = 0.f;
          if (bx != by || col <= row) e = __expf(acc[mi][ni][j] * scale);
          rsum += e;
          Cp[(size_t)row * ldc + col] = f2b(e);
        }
#pragma unroll
        for (int o = 1; o < 16; o <<= 1) rsum += __shfl_xor(rsum, o);
        if (c == 0) atomicAdd(&rowsum[(size_t)bz * M + row], rsum);
      }
  } else {
    float* C = (float*)Cv + (size_t)bz * bsC;
#pragma unroll
    for (int mi = 0; mi < 4; mi++)
#pragma unroll
      for (int j = 0; j < 4; j++) {
        int row = by * BM + wm * 64 + mi * 16 + rb + j;
        float inv = 1.0f / rowsum[(size_t)bz * M + row];
#pragma unroll
        for (int ni = 0; ni < 4; ni++) {
          int col = bx * BN + wn * 64 + ni * 16 + c;
          C[(size_t)row * ldc + col] = acc[mi][ni][j] * inv;
        }
      }
  }
}

// ---------------- bf16 transpose, 64x64 tiles (128B coalesced both sides) ----------------
__global__ __launch_bounds__(256) void transpose2d(const ushort_t* __restrict__ in,
                                                   ushort_t* __restrict__ out,
                                                   int rows, int cols, int ld_in,
                                                   long bs_in, long bs_out) {
  __shared__ ushort_t tile[64][66];
  int b = blockIdx.z;
  in += (size_t)b * bs_in;
  out += (size_t)b * bs_out;
  int c0 = blockIdx.x * 64, r0 = blockIdx.y * 64;
  int tx = threadIdx.x & 31, ty = threadIdx.x >> 5;
#pragma unroll
  for (int i = ty; i < 64; i += 8) {
    ushort2 v = *(const ushort2*)&in[(size_t)(r0 + i) * ld_in + c0 + 2 * tx];
    tile[i][2 * tx] = v.x;
    tile[i][2 * tx + 1] = v.y;
  }
  __syncthreads();
#pragma unroll
  for (int i = ty; i < 64; i += 8) {
    ushort2 o;
    o.x = tile[2 * tx][i];
    o.y = tile[2 * tx + 1][i];
    *(ushort2*)&out[(size_t)(c0 + i) * rows + r0 + 2 * tx] = o;
  }
}

extern "C" void kernel_launch(void* const* d_in, const int* in_sizes, int n_in,
                              void* d_out, int out_size, void* d_ws, size_t ws_size,
                              hipStream_t stream) {
  const int Bb = 4, S = 2048, E = 1024, A = 1024;
  const int N3 = 3 * A;             // fused projection width 3072
  const size_t M = (size_t)Bb * S;  // 8192
  const float* emb = (const float*)d_in[0];
  const float* Wq = (const float*)d_in[1];
  const float* bq = (const float*)d_in[2];
  const float* Wk = (const float*)d_in[3];
  const float* bk = (const float*)d_in[4];
  const float* Wv = (const float*)d_in[5];
  const float* bv = (const float*)d_in[6];
  float* out = (float*)d_out;

  char* ws = (char*)d_ws;
  // layout (byte offsets):
  ushort_t* QKV  = (ushort_t*)(ws + 0);           // 48 MiB [8192][3072]: Q|K|V
  ushort_t* Vt   = (ushort_t*)(ws + 50331648);    // 16 MiB [b][A][S]
  ushort_t* P    = (ushort_t*)(ws + 67108864);    // 32 MiB [b][S][S] bf16 (unnormalized exp)
  float* rowsum  = (float*)(ws + 100663296);      // 32 KiB [b*S]
  ushort_t* embB = (ushort_t*)(ws + 100696064);   // 16 MiB
  ushort_t* WB   = (ushort_t*)(ws + 117473280);   // 6 MiB = Wq|Wk|Wv bf16 [3072][1024]
  float*    bqkv = (float*)(ws + 123764736);      // 12 KiB
  if (ws_size < 157286400ull) return;             // refuse to corrupt

  cvt_kernel<<<2048, 256, 0, stream>>>(emb, embB, (int)(M * E));
  cvt3_kernel<<<dim3(256, 3), 256, 0, stream>>>(Wq, Wk, Wv, WB, A * E);
  concat3_f32<<<4, 256, 0, stream>>>(bq, bk, bv, bqkv, A);
  hipMemsetAsync(rowsum, 0, (size_t)M * sizeof(float), stream);

  // fused QKV projection: M=8192, N=3072, K=1024 -> 24x64 = 1536 blocks, ~3/CU
  gemm_bt<0><<<dim3(N3 / BN, M / BM, 1), dim3(256), 0, stream>>>(
      embB, WB, QKV, bqkv, (int)M, N3, E, E, E, N3, 0, 0, 0, 1.f);

  // V (cols 2048..3071 of QKV, ld 3072) -> Vt [A][S] per batch
  transpose2d<<<dim3(A / 64, S / 64, Bb), dim3(256), 0, stream>>>(
      QKV + 2 * A, Vt, S, A, N3, (long)S * N3, (long)A * S);

  // scores: packed lower-triangle grid, 136 = 8*17 blocks per batch
  gemm_bt<1><<<dim3(136, 1, Bb), dim3(256), 0, stream>>>(
      QKV /*Q*/, QKV + A /*K*/, P, rowsum, S, S, E, N3, N3, S,
      (long)S * N3, (long)S * N3, (long)S * S, 0.03125f);

  // PV: per batch M=2048, N=1024, K=2048 (capped per block-row), divide by rowsum
  gemm_bt<2><<<dim3(A / BN, S / BM, Bb), dim3(256), 0, stream>>>(
      P, Vt, out, rowsum, S, A, S, S, S, A,
      (long)S * S, (long)A * S, (long)S * A, 1.f);
}

// Round 8
// 146.966 us; speedup vs baseline: 1.1104x; 1.0419x over previous
//
#include <hip/hip_runtime.h>
#include <hip/hip_bf16.h>
#include <stdint.h>
#include <math.h>

#define BM 128
#define BN 128
#define BK 64

typedef __attribute__((ext_vector_type(8))) short bf16x8;
typedef __attribute__((ext_vector_type(4))) float f32x4;
typedef unsigned short ushort_t;

__device__ inline unsigned short f2b(float f) {
  unsigned u = __float_as_uint(f);
  unsigned r = (u + 0x7FFFu + ((u >> 16) & 1u)) >> 16;   // RNE, finite inputs
  return (unsigned short)r;
}

__device__ inline void gload_lds16(const void* g, void* l) {
  __builtin_amdgcn_global_load_lds(
      (const __attribute__((address_space(1))) void*)g,
      (__attribute__((address_space(3))) void*)l, 16, 0, 0);
}

// ---------------- fused prep: f32->bf16 (emb + 3 weights), bias concat, rowsum zero ----------------
// replaces 4 graph nodes (cvt, cvt3, concat3, memset) with 1.
// segment sizes hardcoded (problem is fixed-shape): emb 8M elems, each W 1M elems.
#define N_EMB 8388608L   // 8192*1024
#define N_W   1048576L   // 1024*1024 (per weight, = 1<<20)
__global__ __launch_bounds__(256) void prep_kernel(
    const float* __restrict__ emb, const float* __restrict__ Wq,
    const float* __restrict__ Wk, const float* __restrict__ Wv,
    const float* __restrict__ bq, const float* __restrict__ bk,
    const float* __restrict__ bv, ushort_t* __restrict__ embB,
    ushort_t* __restrict__ WB, float* __restrict__ bqkv,
    float* __restrict__ rowsum) {
  long gid = (long)blockIdx.x * blockDim.x + threadIdx.x;
  long stride = (long)gridDim.x * blockDim.x;
  const long tot4 = (N_EMB + 3 * N_W) >> 2;  // float4 count
  for (long i = gid; i < tot4; i += stride) {
    long e = i << 2;
    const float* src;
    ushort_t* dst;
    long off;
    if (e < N_EMB) {
      src = emb; dst = embB; off = e;
    } else {
      long wfl = e - N_EMB;
      int wi = (int)(wfl >> 20);          // /N_W
      off = wfl & (N_W - 1);
      src = wi == 0 ? Wq : (wi == 1 ? Wk : Wv);
      dst = WB + (long)wi * N_W;
    }
    float4 v = *(const float4*)(src + off);
    ushort4 o;
    o.x = f2b(v.x); o.y = f2b(v.y); o.z = f2b(v.z); o.w = f2b(v.w);
    *(ushort4*)(dst + off) = o;
  }
  if (blockIdx.x == 0) {
    for (int i = threadIdx.x; i < 1024; i += 256) {
      bqkv[i] = bq[i];
      bqkv[1024 + i] = bk[i];
      bqkv[2048 + i] = bv[i];
    }
  }
  if (blockIdx.x == 1) {
    for (int i = threadIdx.x; i < 8192; i += 256) rowsum[i] = 0.f;
  }
}

// ---------------- 128x128 GEMM  C = A @ B^T  (A:[M][K], B:[N][K], bf16) ----------------
// BK=64, XOR-swizzled LDS (pre-swizzled global source + swizzled frag read);
// 32 MFMA per barrier; ~3 blocks/CU (cross-block overlap hides stage/drain).
// MODE 0: C bf16 = acc + bias[col]   (projection; 'rowsum' arg = bias, bz=0)
// MODE 1: P bf16 = exp(acc*scale) causal; rowsum atomics.  Grid x = 136 =
//         packed lower-triangle index per batch (8x17 bijective XCD-chunk swizzle).
// MODE 2: C f32  = acc / rowsum[row], K capped at (by+1)*BM (PV).
//         K-balance remap: co-resident block pairs are (i, i+256) which share
//         blockIdx.y; flipping by for bz>=2 pairs Keff (by+1) with (16-by) so
//         every CU carries a constant 17*128 K-rows (removes the 2x71MF pole).
template <int MODE>
__global__ __launch_bounds__(256, 3) void gemm_bt(
    const ushort_t* __restrict__ A, const ushort_t* __restrict__ B,
    void* __restrict__ Cv, float* __restrict__ rowsum,
    int M, int N, int K, int lda, int ldb, int ldc,
    long bsA, long bsB, long bsC, float scale) {
  int bx, by, bz = blockIdx.z;
  if (MODE == 1) {
    // bijective XCD chunk swizzle over 136 blocks, then triangle index -> (by,bx)
    int sw = (blockIdx.x & 7) * 17 + (blockIdx.x >> 3);
    int r = (int)floorf((sqrtf(8.0f * sw + 1.0f) - 1.0f) * 0.5f);
    while ((r + 1) * (r + 2) / 2 <= sw) ++r;
    while (r * (r + 1) / 2 > sw) --r;
    by = r;
    bx = sw - r * (r + 1) / 2;     // bx <= by guaranteed
  } else if (MODE == 2) {
    bx = blockIdx.x;
    by = (bz & 2) ? ((int)gridDim.y - 1 - (int)blockIdx.y) : (int)blockIdx.y;
  } else {
    bx = blockIdx.x;
    by = blockIdx.y;
  }

  const ushort_t* Ab = A + (size_t)bz * bsA + (size_t)by * BM * lda;
  const ushort_t* Bb = B + (size_t)bz * bsB + (size_t)bx * BN * ldb;

  int Keff = K;
  if (MODE == 2) { int cap = (by + 1) * BM; Keff = cap < K ? cap : K; }

  __shared__ __align__(16) ushort_t As[BM * BK];  // 16 KiB
  __shared__ __align__(16) ushort_t Bs[BN * BK];  // 16 KiB

  int tid = threadIdx.x;
  int lane = tid & 63;
  int w = tid >> 6;                 // 4 waves
  int wm = w >> 1, wn = w & 1;

  f32x4 acc[4][4];
#pragma unroll
  for (int i = 0; i < 4; i++)
#pragma unroll
    for (int j = 0; j < 4; j++) acc[i][j] = (f32x4)(0.f);

  // staging: wave w covers rows w*32 .. w*32+31 (4 gload_lds of 8 rows each)
  int srow = lane >> 3;                      // 0..7 within 8-row group
  int scol = ((lane & 7) ^ srow) << 3;       // pre-swizzled source col (elems)
  int fr = lane & 15, g16 = (lane >> 4) * 16;

  int nk = Keff / BK;
  for (int kt = 0; kt < nk; ++kt) {
    const ushort_t* Abase = Ab + (size_t)(w * 32 + srow) * lda + kt * BK + scol;
    const ushort_t* Bbase = Bb + (size_t)(w * 32 + srow) * ldb + kt * BK + scol;
#pragma unroll
    for (int j = 0; j < 4; ++j) {
      gload_lds16(Abase + (size_t)(j * 8) * lda, &As[(w * 32 + j * 8) * BK]);
      gload_lds16(Bbase + (size_t)(j * 8) * ldb, &Bs[(w * 32 + j * 8) * BK]);
    }
    __syncthreads();

    bf16x8 af[4][2], bf[4][2];
#pragma unroll
    for (int i = 0; i < 4; i++)
#pragma unroll
      for (int ks = 0; ks < 2; ++ks) {
        int ra = wm * 64 + i * 16 + fr;
        af[i][ks] = *(const bf16x8*)((const char*)As + ra * 128 +
                                     ((ks * 64 + g16) ^ ((ra & 7) << 4)));
        int rb2 = wn * 64 + i * 16 + fr;
        bf[i][ks] = *(const bf16x8*)((const char*)Bs + rb2 * 128 +
                                     ((ks * 64 + g16) ^ ((rb2 & 7) << 4)));
      }
#pragma unroll
    for (int mi = 0; mi < 4; mi++)
#pragma unroll
      for (int ni = 0; ni < 4; ni++)
#pragma unroll
        for (int ks = 0; ks < 2; ++ks)
          acc[mi][ni] = __builtin_amdgcn_mfma_f32_16x16x32_bf16(
              af[mi][ks], bf[ni][ks], acc[mi][ni], 0, 0, 0);
    __syncthreads();
  }

  int c = lane & 15;
  int rb = (lane >> 4) * 4;
  if (MODE == 0) {
    ushort_t* Cp = (ushort_t*)Cv;
    float bv4[4];
#pragma unroll
    for (int ni = 0; ni < 4; ni++) bv4[ni] = rowsum[bx * BN + wn * 64 + ni * 16 + c];
#pragma unroll
    for (int mi = 0; mi < 4; mi++)
#pragma unroll
      for (int j = 0; j < 4; j++) {
        int row = by * BM + wm * 64 + mi * 16 + rb + j;
#pragma unroll
        for (int ni = 0; ni < 4; ni++) {
          int col = bx * BN + wn * 64 + ni * 16 + c;
          Cp[(size_t)row * ldc + col] = f2b(acc[mi][ni][j] + bv4[ni]);
        }
      }
  } else if (MODE == 1) {
    ushort_t* Cp = (ushort_t*)Cv + (size_t)bz * bsC;
#pragma unroll
    for (int mi = 0; mi < 4; mi++)
#pragma unroll
      for (int j = 0; j < 4; j++) {
        int row = by * BM + wm * 64 + mi * 16 + rb + j;
        float rsum = 0.f;
#pragma unroll
        for (int ni = 0; ni < 4; ni++) {
          int col = bx * BN + wn * 64 + ni * 16 + c;
          float e = 0.f;
          if (bx != by || col <= row) e = __expf(acc[mi][ni][j] * scale);
          rsum += e;
          Cp[(size_t)row * ldc + col] = f2b(e);
        }
#pragma unroll
        for (int o = 1; o < 16; o <<= 1) rsum += __shfl_xor(rsum, o);
        if (c == 0) atomicAdd(&rowsum[(size_t)bz * M + row], rsum);
      }
  } else {
    float* C = (float*)Cv + (size_t)bz * bsC;
#pragma unroll
    for (int mi = 0; mi < 4; mi++)
#pragma unroll
      for (int j = 0; j < 4; j++) {
        int row = by * BM + wm * 64 + mi * 16 + rb + j;
        float inv = 1.0f / rowsum[(size_t)bz * M + row];
#pragma unroll
        for (int ni = 0; ni < 4; ni++) {
          int col = bx * BN + wn * 64 + ni * 16 + c;
          C[(size_t)row * ldc + col] = acc[mi][ni][j] * inv;
        }
      }
  }
}

// ---------------- bf16 transpose, 64x64 tiles (128B coalesced both sides) ----------------
__global__ __launch_bounds__(256) void transpose2d(const ushort_t* __restrict__ in,
                                                   ushort_t* __restrict__ out,
                                                   int rows, int cols, int ld_in,
                                                   long bs_in, long bs_out) {
  __shared__ ushort_t tile[64][66];
  int b = blockIdx.z;
  in += (size_t)b * bs_in;
  out += (size_t)b * bs_out;
  int c0 = blockIdx.x * 64, r0 = blockIdx.y * 64;
  int tx = threadIdx.x & 31, ty = threadIdx.x >> 5;
#pragma unroll
  for (int i = ty; i < 64; i += 8) {
    ushort2 v = *(const ushort2*)&in[(size_t)(r0 + i) * ld_in + c0 + 2 * tx];
    tile[i][2 * tx] = v.x;
    tile[i][2 * tx + 1] = v.y;
  }
  __syncthreads();
#pragma unroll
  for (int i = ty; i < 64; i += 8) {
    ushort2 o;
    o.x = tile[2 * tx][i];
    o.y = tile[2 * tx + 1][i];
    *(ushort2*)&out[(size_t)(c0 + i) * rows + r0 + 2 * tx] = o;
  }
}

extern "C" void kernel_launch(void* const* d_in, const int* in_sizes, int n_in,
                              void* d_out, int out_size, void* d_ws, size_t ws_size,
                              hipStream_t stream) {
  const int Bb = 4, S = 2048, E = 1024, A = 1024;
  const int N3 = 3 * A;             // fused projection width 3072
  const size_t M = (size_t)Bb * S;  // 8192
  const float* emb = (const float*)d_in[0];
  const float* Wq = (const float*)d_in[1];
  const float* bq = (const float*)d_in[2];
  const float* Wk = (const float*)d_in[3];
  const float* bk = (const float*)d_in[4];
  const float* Wv = (const float*)d_in[5];
  const float* bv = (const float*)d_in[6];
  float* out = (float*)d_out;

  char* ws = (char*)d_ws;
  // layout (byte offsets):
  ushort_t* QKV  = (ushort_t*)(ws + 0);           // 48 MiB [8192][3072]: Q|K|V
  ushort_t* Vt   = (ushort_t*)(ws + 50331648);    // 16 MiB [b][A][S]
  ushort_t* P    = (ushort_t*)(ws + 67108864);    // 32 MiB [b][S][S] bf16 (unnormalized exp)
  float* rowsum  = (float*)(ws + 100663296);      // 32 KiB [b*S]
  ushort_t* embB = (ushort_t*)(ws + 100696064);   // 16 MiB
  ushort_t* WB   = (ushort_t*)(ws + 117473280);   // 6 MiB = Wq|Wk|Wv bf16 [3072][1024]
  float*    bqkv = (float*)(ws + 123764736);      // 12 KiB
  if (ws_size < 157286400ull) return;             // refuse to corrupt

  // fused prep: emb+weights f32->bf16, bias concat, rowsum zero (1 node, was 4)
  prep_kernel<<<2048, 256, 0, stream>>>(emb, Wq, Wk, Wv, bq, bk, bv,
                                        embB, WB, bqkv, rowsum);

  // fused QKV projection: M=8192, N=3072, K=1024 -> 24x64 = 1536 blocks, ~3/CU
  gemm_bt<0><<<dim3(N3 / BN, M / BM, 1), dim3(256), 0, stream>>>(
      embB, WB, QKV, bqkv, (int)M, N3, E, E, E, N3, 0, 0, 0, 1.f);

  // V (cols 2048..3071 of QKV, ld 3072) -> Vt [A][S] per batch
  transpose2d<<<dim3(A / 64, S / 64, Bb), dim3(256), 0, stream>>>(
      QKV + 2 * A, Vt, S, A, N3, (long)S * N3, (long)A * S);

  // scores: packed lower-triangle grid, 136 = 8*17 blocks per batch
  gemm_bt<1><<<dim3(136, 1, Bb), dim3(256), 0, stream>>>(
      QKV /*Q*/, QKV + A /*K*/, P, rowsum, S, S, E, N3, N3, S,
      (long)S * N3, (long)S * N3, (long)S * S, 0.03125f);

  // PV: per batch M=2048, N=1024, K=2048 (capped per block-row), divide by rowsum
  gemm_bt<2><<<dim3(A / BN, S / BM, Bb), dim3(256), 0, stream>>>(
      P, Vt, out, rowsum, S, A, S, S, S, A,
      (long)S * S, (long)A * S, (long)S * A, 1.f);
}